// Round 7
// baseline (41445.938 us; speedup 1.0000x reference)
//
#include <hip/hip_runtime.h>
#include <stdint.h>
#include <math.h>

#define T_STEPS 1000

typedef __attribute__((ext_vector_type(4))) float f32x4;
typedef __attribute__((ext_vector_type(8))) _Float16 f16x8;
typedef __attribute__((ext_vector_type(4))) int i32x4;

#define C_2M11 4.8828125e-4f         // 2^-11
#define C_2M22 2.384185791015625e-7f // 2^-22
#define F16_MINNORM 6.103515625e-05f

__device__ __forceinline__ void split2h(float v, _Float16& hi, _Float16& lo) {
    float av = fabsf(v);
    _Float16 h = (av < F16_MINNORM) ? (_Float16)0.0f : (_Float16)v;
    float r = v - (float)h;
    hi = h;
    lo = (_Float16)(r * 2048.0f);
}
__device__ __forceinline__ short f2s(_Float16 h) {
    union { _Float16 h; short s; } u; u.h = h; return u.s;
}
// pack both limbs of one value into a dword: low16 = hi-limb, high16 = lo-limb
__device__ __forceinline__ int packh(float v) {
    _Float16 hi, lo;
    split2h(v, hi, lo);
    return (int)(unsigned short)f2s(hi) | ((int)(unsigned short)f2s(lo) << 16);
}
// unpack 8 packed ints (A,B) -> hi-limb f16x8 and lo-limb f16x8 (verified R6)
__device__ __forceinline__ void unpack8(i32x4 A, i32x4 B, f16x8& hi, f16x8& lo) {
    union { unsigned u[4]; f16x8 h; } H, L;
    H.u[0] = __builtin_amdgcn_perm((unsigned)A[1], (unsigned)A[0], 0x05040100u);
    H.u[1] = __builtin_amdgcn_perm((unsigned)A[3], (unsigned)A[2], 0x05040100u);
    H.u[2] = __builtin_amdgcn_perm((unsigned)B[1], (unsigned)B[0], 0x05040100u);
    H.u[3] = __builtin_amdgcn_perm((unsigned)B[3], (unsigned)B[2], 0x05040100u);
    L.u[0] = __builtin_amdgcn_perm((unsigned)A[1], (unsigned)A[0], 0x07060302u);
    L.u[1] = __builtin_amdgcn_perm((unsigned)A[3], (unsigned)A[2], 0x07060302u);
    L.u[2] = __builtin_amdgcn_perm((unsigned)B[1], (unsigned)B[0], 0x07060302u);
    L.u[3] = __builtin_amdgcn_perm((unsigned)B[3], (unsigned)B[2], 0x07060302u);
    hi = H.h;
    lo = L.h;
}

#define MFMAH(a, b, c) __builtin_amdgcn_mfma_f32_16x16x32_f16((a), (b), (c), 0, 0, 0)

// ---------------- coefficients ----------------
__global__ void scalars_kernel(float* As, float* Bc, float* Dc) {
    if (threadIdx.x == 0 && blockIdx.x == 0) {
        float acp = 1.0f, ac_prev = 1.0f;
        for (int t = 0; t < T_STEPS; ++t) {
            float beta = (float)(1.0e-4 + (double)t * ((0.02 - 1.0e-4) / 999.0));
            acp = acp * (1.0f - beta);
            int i = (T_STEPS - 1) - t;
            As[i] = sqrtf(acp);
            Bc[i] = sqrtf(1.0f - acp);
            Dc[i] = sqrtf(1.0f - ac_prev) + sqrtf(beta);
            ac_prev = acp;
        }
    }
}

// ---------------- silu time features ----------------
__global__ __launch_bounds__(256) void feats_kernel(const float* tw1, const float* tb1, float* s) {
    int idx = blockIdx.x * 256 + threadIdx.x;
    if (idx < T_STEPS * 512) {
        int t = idx >> 9, m = idx & 511;
        float a = (float)t * tw1[m] + tb1[m];
        s[idx] = a / (1.0f + expf(-a));
    }
}

// ---------------- fp32 GEMM: C[M,512] = A[M,512] @ B[512,512] + bias ----------------
__global__ __launch_bounds__(256) void gemm_kernel(const float* A, const float* B,
                                                   const float* bias, float* C, int M) {
    __shared__ float Asm[16][68];
    __shared__ float Bsm[16][68];
    int tx = threadIdx.x & 15, ty = threadIdx.x >> 4;
    int m0 = blockIdx.x * 64, n0 = blockIdx.y * 64;
    float acc[4][4] = {};
    for (int k0 = 0; k0 < 512; k0 += 16) {
        for (int l = 0; l < 4; ++l) {
            int e = threadIdx.x + l * 256;
            int mm = e >> 4, kk = e & 15;
            Asm[kk][mm] = (m0 + mm < M) ? A[(size_t)(m0 + mm) * 512 + k0 + kk] : 0.0f;
            int nn = e & 63, kk2 = e >> 6;
            Bsm[kk2][nn] = B[(size_t)(k0 + kk2) * 512 + n0 + nn];
        }
        __syncthreads();
        for (int kk = 0; kk < 16; ++kk) {
            float a[4], b[4];
            for (int i = 0; i < 4; ++i) a[i] = Asm[kk][ty * 4 + i];
            for (int j = 0; j < 4; ++j) b[j] = Bsm[kk][tx * 4 + j];
            for (int i = 0; i < 4; ++i)
                for (int j = 0; j < 4; ++j) acc[i][j] += a[i] * b[j];
        }
        __syncthreads();
    }
    for (int i = 0; i < 4; ++i) {
        int m = m0 + ty * 4 + i;
        if (m < M)
            for (int j = 0; j < 4; ++j) {
                int n = n0 + tx * 4 + j;
                C[(size_t)m * 512 + n] = acc[i][j] + bias[n];
            }
    }
}

// ---------------- pack weight fragment-order + 2-limb fp16 split ----------------
// plane layout: [nblk16:32][kb:16][nlocal:16][klocal:32] shorts
__global__ __launch_bounds__(256) void tpack_kernel(const float* w, short* ph, short* pl) {
    int p = blockIdx.x * 256 + threadIdx.x;
    if (p < 512 * 512) {
        int chunk = p >> 9, inch = p & 511;
        int n = (chunk >> 4) * 16 + (inch >> 5);
        int k = (chunk & 15) * 32 + (inch & 31);
        float v = w[(size_t)k * 512 + n];
        _Float16 hi, lo;
        split2h(v, hi, lo);
        ph[p] = f2s(hi);
        pl[p] = f2s(lo);
    }
}

// ---------------- main loop: 16 blocks x 256 threads, ZERO inter-block comm ----
// Block owns 16 batch rows. 4 waves; wave wv owns output cols wv*128..+127.
// x and h live in LDS as packed ints in EXACT MFMA-read order:
//   plane[((n>>3)*16 + m)*8 + (n&7)]  ->  read addr = kb*2048B + lane*32B
// (perfectly linear per wave: conflict-free ds_read_b128 pairs).
// Weights stream from L2 (2 MB/block/step, 2 blocks/XCD -> ~1 us, hidden).
__global__ __launch_bounds__(256, 1) void diffusion_main(
    const float* x0,
    const short* w1h_, const short* w1l_,
    const short* w2h_, const short* w2l_,
    const float* tep, const float* nb2,
    const float* As, const float* Bc, const float* Dc,
    const float* dw1, const float* db1, const float* dw2, const float* db2,
    const float* ew1, const float* eb1, const float* ew2, const float* eb2,
    float* out) {

    __shared__ int xlds[8192];   // 16 rows x 512 cols, packed 2-limb
    __shared__ int hlds[8192];   // ditto for h; reused as head-reduction scratch

    const int tid = threadIdx.x;
    const int wv = tid >> 6;
    const int lane = tid & 63;
    const int l15 = lane & 15, lg = lane >> 4;
    const int b0 = blockIdx.x * 16;
    const int c0 = wv * 128;
    const int aoff = l15 * 32 + lg * 8;   // weight fragment offset (shorts)

    const short* w1hW = w1h_ + (size_t)(wv * 8) * 8192;
    const short* w1lW = w1l_ + (size_t)(wv * 8) * 8192;
    const short* w2hW = w2h_ + (size_t)(wv * 8) * 8192;
    const short* w2lW = w2l_ + (size_t)(wv * 8) * 8192;

    // ---- init: load x0 slice, keep fp32 in regs, publish packed to LDS ----
    float xr[8][4], nb2r[8];
#pragma unroll
    for (int nt = 0; nt < 8; ++nt) {
        int n = c0 + nt * 16 + l15;
        nb2r[nt] = nb2[n];
#pragma unroll
        for (int r = 0; r < 4; ++r) {
            float v = x0[(size_t)(b0 + lg * 4 + r) * 512 + n];
            xr[nt][r] = v;
            xlds[((n >> 3) * 16 + lg * 4 + r) * 8 + (n & 7)] = packh(v);
        }
    }
    __syncthreads();

#pragma unroll 1
    for (int i = 0; i < T_STEPS; ++i) {
        const int t = (T_STEPS - 1) - i;
        const float a_s = As[i], bc = Bc[i], dc = Dc[i];
        float tep_r[8];
#pragma unroll
        for (int nt = 0; nt < 8; ++nt)
            tep_r[nt] = tep[(size_t)t * 512 + c0 + nt * 16 + l15];

        // ---- GEMM1: h = relu(x @ W1 + tep) ----
        f32x4 A0[8], A1[8], A2[8];
#pragma unroll
        for (int nt = 0; nt < 8; ++nt) {
            A0[nt] = (f32x4){0.f, 0.f, 0.f, 0.f};
            A1[nt] = (f32x4){0.f, 0.f, 0.f, 0.f};
            A2[nt] = (f32x4){0.f, 0.f, 0.f, 0.f};
        }
#pragma unroll 2
        for (int kb = 0; kb < 16; ++kb) {
            i32x4 pA = *(const i32x4*)&xlds[kb * 512 + lane * 8];
            i32x4 pB = *(const i32x4*)&xlds[kb * 512 + lane * 8 + 4];
            f16x8 ah, al;
            unpack8(pA, pB, ah, al);
#pragma unroll
            for (int nt = 0; nt < 8; ++nt) {
                f16x8 bh = *(const f16x8*)(w1hW + ((nt * 16 + kb) << 9) + aoff);
                f16x8 bl = *(const f16x8*)(w1lW + ((nt * 16 + kb) << 9) + aoff);
                A0[nt] = MFMAH(ah, bh, A0[nt]);
                A1[nt] = MFMAH(ah, bl, A1[nt]);
                A1[nt] = MFMAH(al, bh, A1[nt]);
                A2[nt] = MFMAH(al, bl, A2[nt]);
            }
        }
#pragma unroll
        for (int nt = 0; nt < 8; ++nt)
#pragma unroll
            for (int r = 0; r < 4; ++r) {
                float hv = A0[nt][r] + A1[nt][r] * C_2M11 + A2[nt][r] * C_2M22 + tep_r[nt];
                hv = hv > 0.f ? hv : 0.f;
                int n = c0 + nt * 16 + l15;
                hlds[((n >> 3) * 16 + lg * 4 + r) * 8 + (n & 7)] = packh(hv);
            }
        __syncthreads();

        // ---- GEMM2: eps = h @ W2 + nb2; x update ----
#pragma unroll
        for (int nt = 0; nt < 8; ++nt) {
            A0[nt] = (f32x4){0.f, 0.f, 0.f, 0.f};
            A1[nt] = (f32x4){0.f, 0.f, 0.f, 0.f};
            A2[nt] = (f32x4){0.f, 0.f, 0.f, 0.f};
        }
#pragma unroll 2
        for (int kb = 0; kb < 16; ++kb) {
            i32x4 pA = *(const i32x4*)&hlds[kb * 512 + lane * 8];
            i32x4 pB = *(const i32x4*)&hlds[kb * 512 + lane * 8 + 4];
            f16x8 ah, al;
            unpack8(pA, pB, ah, al);
#pragma unroll
            for (int nt = 0; nt < 8; ++nt) {
                f16x8 bh = *(const f16x8*)(w2hW + ((nt * 16 + kb) << 9) + aoff);
                f16x8 bl = *(const f16x8*)(w2lW + ((nt * 16 + kb) << 9) + aoff);
                A0[nt] = MFMAH(ah, bh, A0[nt]);
                A1[nt] = MFMAH(ah, bl, A1[nt]);
                A1[nt] = MFMAH(al, bh, A1[nt]);
                A2[nt] = MFMAH(al, bl, A2[nt]);
            }
        }
#pragma unroll
        for (int nt = 0; nt < 8; ++nt)
#pragma unroll
            for (int r = 0; r < 4; ++r) {
                float eps = A0[nt][r] + A1[nt][r] * C_2M11 + A2[nt][r] * C_2M22 + nb2r[nt];
                float xv = (xr[nt][r] - bc * eps) / a_s + dc * eps;
                xv = fminf(fmaxf(xv, -1000.0f), 1000.0f);
                xr[nt][r] = xv;
                int n = c0 + nt * 16 + l15;
                xlds[((n >> 3) * 16 + lg * 4 + r) * 8 + (n & 7)] = packh(xv);
            }
        __syncthreads();
    }

    // ---- epilogue: write final x ----
#pragma unroll
    for (int nt = 0; nt < 8; ++nt)
#pragma unroll
        for (int r = 0; r < 4; ++r)
            out[(size_t)(b0 + lg * 4 + r) * 515 + 3 + c0 + nt * 16 + l15] = xr[nt][r];

    // ---- heads: thread -> row m=l15, hidden cols cbase..cbase+15 ----
    {
        const int cbase = (wv * 4 + lg) * 16;
        float ad[16], ae[16];
#pragma unroll
        for (int j = 0; j < 16; ++j) { ad[j] = 0.f; ae[j] = 0.f; }
#pragma unroll 4
        for (int k = 0; k < 512; ++k) {
            int pv = xlds[((k >> 3) * 16 + l15) * 8 + (k & 7)];
            union { short s; _Float16 h; } uh, ul;
            uh.s = (short)(pv & 0xffff);
            ul.s = (short)((unsigned)pv >> 16);
            float xv = (float)uh.h + (float)ul.h * C_2M11;
            const f32x4* wd = (const f32x4*)(dw1 + (size_t)k * 256 + cbase);
            const f32x4* we = (const f32x4*)(ew1 + (size_t)k * 256 + cbase);
#pragma unroll
            for (int q = 0; q < 4; ++q) {
                f32x4 wdq = wd[q], weq = we[q];
#pragma unroll
                for (int j = 0; j < 4; ++j) {
                    ad[q * 4 + j] += xv * wdq[j];
                    ae[q * 4 + j] += xv * weq[j];
                }
            }
        }
        float sd = 0.f, se1 = 0.f, se2 = 0.f;
#pragma unroll
        for (int j = 0; j < 16; ++j) {
            int c = cbase + j;
            float hdv = ad[j] + db1[c]; hdv = hdv > 0.f ? hdv : 0.f;
            float hev = ae[j] + eb1[c]; hev = hev > 0.f ? hev : 0.f;
            sd  += hdv * dw2[c];
            se1 += hev * ew2[2 * c];
            se2 += hev * ew2[2 * c + 1];
        }
        __syncthreads();   // xlds reads done; hlds free for reduction scratch
        float* hred = (float*)hlds;   // [3][16 chunk][16 m]
        int chunk = wv * 4 + lg;
        hred[(0 * 16 + chunk) * 16 + l15] = sd;
        hred[(1 * 16 + chunk) * 16 + l15] = se1;
        hred[(2 * 16 + chunk) * 16 + l15] = se2;
    }
    __syncthreads();
    if (tid < 16) {
        const float* hred = (const float*)hlds;
        float s0 = 0.f, s1 = 0.f, s2 = 0.f;
        for (int c = 0; c < 16; ++c) {
            s0 += hred[(0 * 16 + c) * 16 + tid];
            s1 += hred[(1 * 16 + c) * 16 + tid];
            s2 += hred[(2 * 16 + c) * 16 + tid];
        }
        out[(size_t)(b0 + tid) * 515 + 0] = s0 + db2[0];
        out[(size_t)(b0 + tid) * 515 + 1] = s1 + eb2[0];
        out[(size_t)(b0 + tid) * 515 + 2] = s2 + eb2[1];
    }
}

extern "C" void kernel_launch(void* const* d_in, const int* in_sizes, int n_in,
                              void* d_out, int out_size, void* d_ws, size_t ws_size,
                              hipStream_t stream) {
    const float* x0  = (const float*)d_in[0];
    const float* tw1 = (const float*)d_in[1];
    const float* tb1 = (const float*)d_in[2];
    const float* tw2 = (const float*)d_in[3];
    const float* tb2 = (const float*)d_in[4];
    const float* nw1 = (const float*)d_in[5];
    const float* nb1 = (const float*)d_in[6];
    const float* nw2 = (const float*)d_in[7];
    const float* nb2 = (const float*)d_in[8];
    const float* dw1 = (const float*)d_in[9];
    const float* db1 = (const float*)d_in[10];
    const float* dw2 = (const float*)d_in[11];
    const float* db2 = (const float*)d_in[12];
    const float* ew1 = (const float*)d_in[13];
    const float* eb1 = (const float*)d_in[14];
    const float* ew2 = (const float*)d_in[15];
    const float* eb2 = (const float*)d_in[16];
    float* out = (float*)d_out;

    float* ws    = (float*)d_ws;
    float* sfeat = ws;                   // 512000 f
    float* te    = sfeat + 512000;       // 512000 f
    float* tep   = te + 512000;          // 512000 f
    float* Asv   = tep + 512000;         // 1024 f each
    float* Bcv   = Asv + 1024;
    float* Dcv   = Bcv + 1024;
    short* w1h   = (short*)(Dcv + 1024); // 4 planes x 262144 shorts
    short* w1l   = w1h + 262144;
    short* w2h   = w1l + 262144;
    short* w2l   = w2h + 262144;

    hipLaunchKernelGGL(scalars_kernel, dim3(1), dim3(64), 0, stream, Asv, Bcv, Dcv);
    hipLaunchKernelGGL(feats_kernel, dim3(2000), dim3(256), 0, stream, tw1, tb1, sfeat);
    hipLaunchKernelGGL(gemm_kernel, dim3(16, 8), dim3(256), 0, stream, sfeat, tw2, tb2, te, 1000);
    hipLaunchKernelGGL(gemm_kernel, dim3(16, 8), dim3(256), 0, stream, te, nw1 + 512 * 512, nb1, tep, 1000);
    hipLaunchKernelGGL(tpack_kernel, dim3(1024), dim3(256), 0, stream, nw1, w1h, w1l);
    hipLaunchKernelGGL(tpack_kernel, dim3(1024), dim3(256), 0, stream, nw2, w2h, w2l);
    hipLaunchKernelGGL(diffusion_main, dim3(16), dim3(256), 0, stream,
                       x0, w1h, w1l, w2h, w2l,
                       tep, nb2, Asv, Bcv, Dcv,
                       dw1, db1, dw2, db2, ew1, eb1, ew2, eb2, out);
}